// Round 2
// baseline (8645.766 us; speedup 1.0000x reference)
//
#include <hip/hip_runtime.h>

#define B_ 4
#define N_ 40000
#define E_ 240000

typedef unsigned short u16;
typedef unsigned int u32;

__device__ __forceinline__ float b2f(u16 h) {
    u32 u = ((u32)h) << 16;
    return __uint_as_float(u);
}
__device__ __forceinline__ u16 f2b(float f) {
    u32 u = __float_as_uint(f);
    u32 r = (u + 0x7fffu + ((u >> 16) & 1u)) >> 16;
    return (u16)r;
}
__device__ __forceinline__ float4 f4_zero() { return make_float4(0.f, 0.f, 0.f, 0.f); }

// ---------------- first linear: x = x_in @ w_first + b_first (bf16 out) ----------------
__global__ __launch_bounds__(256) void first_linear_kern(
    const float* __restrict__ x_in, const float* __restrict__ w,
    const float* __restrict__ bias, u16* __restrict__ xout, int M)
{
    __shared__ float sw[6 * 128];
    __shared__ float sb[128];
    int t = threadIdx.x;
    for (int i = t; i < 768; i += 256) sw[i] = w[i];
    if (t < 128) sb[t] = bias[t];
    __syncthreads();
    int idx = blockIdx.x * 256 + t;
    int row = idx >> 7;
    int c = idx & 127;
    if (row >= M) return;
    const float* xr = x_in + (size_t)row * 6;
    float acc = sb[c];
#pragma unroll
    for (int j = 0; j < 6; j++) acc += xr[j] * sw[j * 128 + c];
    xout[(size_t)row * 128 + c] = f2b(acc);
}

// ------------- spectral projection stage 1 (deterministic partials) -------------
// partial[(b*128+pb)][k][c] = sum_{n in chunks of pb} ev[b,n,k]*mass[b,n]*x[b,n,c]
__global__ __launch_bounds__(256) void spec_stage1_kern(
    const u16* __restrict__ x, const float* __restrict__ mass,
    const float* __restrict__ evecs, float* __restrict__ partials)
{
    __shared__ float sEV[32][128];
    __shared__ float sXM[32][128];
    int b = blockIdx.y;
    int pb = blockIdx.x;
    const u16* xb = x + (size_t)b * N_ * 128;
    const float* mb = mass + (size_t)b * N_;
    const float* eb = evecs + (size_t)b * N_ * 128;
    float* dstSlab = partials + ((size_t)b * 128 + pb) * 16384;

    int t = threadIdx.x;
    int c4 = (t & 31) * 4;
    int k0 = (t >> 5) * 16;
    float4 acc[16];
#pragma unroll
    for (int i = 0; i < 16; i++) acc[i] = f4_zero();

    for (int ch = pb; ch < N_ / 32; ch += 128) {
        int n0 = ch * 32;
#pragma unroll
        for (int p = 0; p < 4; p++) {
            int elem = (p * 256 + t) * 4;
            int nn = elem >> 7;
            int kk = elem & 127;
            *(float4*)&sEV[nn][kk] = *(const float4*)(eb + (size_t)(n0 + nn) * 128 + kk);
            float mm = mb[n0 + nn];
            ushort4 xh = *(const ushort4*)(xb + (size_t)(n0 + nn) * 128 + kk);
            float4 xv;
            xv.x = b2f(xh.x) * mm; xv.y = b2f(xh.y) * mm;
            xv.z = b2f(xh.z) * mm; xv.w = b2f(xh.w) * mm;
            *(float4*)&sXM[nn][kk] = xv;
        }
        __syncthreads();
#pragma unroll 2
        for (int nn = 0; nn < 32; nn++) {
            float4 xv = *(const float4*)&sXM[nn][c4];
#pragma unroll
            for (int i = 0; i < 16; i++) {
                float ev = sEV[nn][k0 + i];
                acc[i].x += ev * xv.x;
                acc[i].y += ev * xv.y;
                acc[i].z += ev * xv.z;
                acc[i].w += ev * xv.w;
            }
        }
        __syncthreads();
    }
#pragma unroll
    for (int i = 0; i < 16; i++)
        *(float4*)(dstSlab + (size_t)(k0 + i) * 128 + c4) = acc[i];
}

// ------------- stage 2 + coefficients: ys[b,k,c] = exp(-evals*dt) * sum_pb partial -------------
__global__ __launch_bounds__(128) void spec_stage2_coef_kern(
    const float* __restrict__ partials, const float* __restrict__ evals,
    const float* __restrict__ dt, float* __restrict__ ys)
{
    int b = blockIdx.x >> 7;
    int k = blockIdx.x & 127;
    int c = threadIdx.x;
    const float* p = partials + (size_t)b * 128 * 16384 + (size_t)k * 128 + c;
    float s = 0.f;
#pragma unroll 8
    for (int pb = 0; pb < 128; pb++) s += p[(size_t)pb * 16384];
    float co = expf(-evals[b * 128 + k] * dt[c]);
    ys[((size_t)b * 128 + k) * 128 + c] = s * co;
}

// ------------- generic tiled GEMM: out[m,0:128] = act(A[m,:KKT] @ W + bias + resid) -------------
template <int KKT, bool CONCAT3, bool RELU, bool RESID, bool HASBIAS, bool ABF16, bool OBF16>
__global__ __launch_bounds__(256) void gemm128_kern(
    const void* __restrict__ A0v, const void* __restrict__ A1v, const void* __restrict__ A2v,
    const float* __restrict__ W, const float* __restrict__ bias,
    const u16* __restrict__ resid, void* __restrict__ outv,
    size_t aBatch, size_t wBatch, size_t oBatch)
{
    __shared__ float sA[64][32];
    __shared__ float sW[32][128];
    int b = blockIdx.z;
    const float* Wb = W + wBatch * (size_t)b;
    size_t aOff = aBatch * (size_t)b;
    size_t oOff = oBatch * (size_t)b;

    int t = threadIdx.x;
    int m0 = blockIdx.x * 64;
    int c4 = (t & 31) * 4;
    int r8 = (t >> 5) * 8;
    float4 acc[8];
#pragma unroll
    for (int i = 0; i < 8; i++) acc[i] = f4_zero();

    constexpr int NT = KKT / 32;
#pragma unroll 1
    for (int kt = 0; kt < NT; kt++) {
        int kbase = kt * 32;
        const void* Aptr;
        if (CONCAT3) {
            Aptr = (kbase < 128) ? A0v : (kbase < 256) ? A1v : A2v;
        } else {
            Aptr = A0v;
        }
        int kloc = kbase & 127;
        {
            int row = t >> 3;
            int k4 = (t & 7) * 4;
#pragma unroll
            for (int p = 0; p < 2; p++) {
                int r = row + p * 32;
                size_t off = aOff + (size_t)(m0 + r) * 128 + kloc + k4;
                if (ABF16) {
                    ushort4 h = *((const ushort4*)Aptr + 0);  // placate compiler; real load below
                    h = *(const ushort4*)((const u16*)Aptr + off);
                    sA[r][k4 + 0] = b2f(h.x);
                    sA[r][k4 + 1] = b2f(h.y);
                    sA[r][k4 + 2] = b2f(h.z);
                    sA[r][k4 + 3] = b2f(h.w);
                } else {
                    *(float4*)&sA[r][k4] = *(const float4*)((const float*)Aptr + off);
                }
            }
        }
        {
#pragma unroll
            for (int p = 0; p < 4; p++) {
                int elem = (p * 256 + t) * 4;
                int kr = elem >> 7;
                int cc = elem & 127;
                *(float4*)&sW[kr][cc] = *(const float4*)(Wb + (size_t)(kbase + kr) * 128 + cc);
            }
        }
        __syncthreads();
#pragma unroll
        for (int kk = 0; kk < 32; kk += 4) {
            float4 w0 = *(const float4*)&sW[kk + 0][c4];
            float4 w1 = *(const float4*)&sW[kk + 1][c4];
            float4 w2 = *(const float4*)&sW[kk + 2][c4];
            float4 w3 = *(const float4*)&sW[kk + 3][c4];
#pragma unroll
            for (int i = 0; i < 8; i++) {
                float4 a = *(const float4*)&sA[r8 + i][kk];
                acc[i].x += a.x * w0.x + a.y * w1.x + a.z * w2.x + a.w * w3.x;
                acc[i].y += a.x * w0.y + a.y * w1.y + a.z * w2.y + a.w * w3.y;
                acc[i].z += a.x * w0.z + a.y * w1.z + a.z * w2.z + a.w * w3.z;
                acc[i].w += a.x * w0.w + a.y * w1.w + a.z * w2.w + a.w * w3.w;
            }
        }
        __syncthreads();
    }
    float4 bv = f4_zero();
    if (HASBIAS) bv = *(const float4*)(bias + c4);
#pragma unroll
    for (int i = 0; i < 8; i++) {
        size_t o = (size_t)(m0 + r8 + i) * 128 + c4;
        float4 v = acc[i];
        v.x += bv.x; v.y += bv.y; v.z += bv.z; v.w += bv.w;
        if (RESID) {
            ushort4 rh = *(const ushort4*)(resid + o);
            v.x += b2f(rh.x); v.y += b2f(rh.y); v.z += b2f(rh.z); v.w += b2f(rh.w);
        }
        if (RELU) {
            v.x = fmaxf(v.x, 0.f); v.y = fmaxf(v.y, 0.f);
            v.z = fmaxf(v.z, 0.f); v.w = fmaxf(v.w, 0.f);
        }
        if (OBF16) {
            ushort4 sv;
            sv.x = f2b(v.x); sv.y = f2b(v.y); sv.z = f2b(v.z); sv.w = f2b(v.w);
            *(ushort4*)((u16*)outv + oOff + o) = sv;
        } else {
            *(float4*)((float*)outv + oOff + o) = v;
        }
    }
}

// ------------- single-batch dual COO spMM: gX/gY[row,:] += valX/valY[e] * xd[col,:] -------------
__global__ __launch_bounds__(256) void spmm_dual_b_kern(
    const int* __restrict__ rows, const int* __restrict__ cols,
    const float* __restrict__ vx, const float* __restrict__ vy,
    const u16* __restrict__ xd_b, float* gXf, float* gYf)
{
    int idx = blockIdx.x * 256 + threadIdx.x;
    int e = idx >> 7;
    if (e >= E_) return;
    int c = idx & 127;
    int r = rows[e];
    int col = cols[e];
    float xv = b2f(xd_b[(size_t)col * 128 + c]);
    atomicAdd(gXf + (size_t)r * 128 + c, vx[e] * xv);
    atomicAdd(gYf + (size_t)r * 128 + c, vy[e] * xv);
}

// ------------- rotation + tanh (single batch): gf = tanh(gX*Breal + gY*Bimag) -------------
__global__ __launch_bounds__(256) void rotate_b_kern(
    const float* __restrict__ gXf, const float* __restrict__ gYf,
    const float* __restrict__ Are, const float* __restrict__ Aim,
    u16* __restrict__ gf_b)
{
    __shared__ float sGX[32][32];
    __shared__ float sGY[32][32];
    __shared__ float sAre[32][128];
    __shared__ float sAim[32][128];
    int t = threadIdx.x;
    int m0 = blockIdx.x * 32;
    int c4 = (t & 31) * 4;
    int r4 = (t >> 5) * 4;
    float4 accRe[4], accIm[4];
#pragma unroll
    for (int i = 0; i < 4; i++) { accRe[i] = f4_zero(); accIm[i] = f4_zero(); }

    for (int kt = 0; kt < 4; kt++) {
        int kb = kt * 32;
        {
            int nn = t >> 3;
            int kk = (t & 7) * 4;
            *(float4*)&sGX[nn][kk] = *(const float4*)(gXf + (size_t)(m0 + nn) * 128 + kb + kk);
            *(float4*)&sGY[nn][kk] = *(const float4*)(gYf + (size_t)(m0 + nn) * 128 + kb + kk);
        }
#pragma unroll
        for (int p = 0; p < 4; p++) {
            int elem = (p * 256 + t) * 4;
            int kr = elem >> 7;
            int cc = elem & 127;
            *(float4*)&sAre[kr][cc] = *(const float4*)(Are + (size_t)(kb + kr) * 128 + cc);
            *(float4*)&sAim[kr][cc] = *(const float4*)(Aim + (size_t)(kb + kr) * 128 + cc);
        }
        __syncthreads();
#pragma unroll 4
        for (int kk = 0; kk < 32; kk++) {
            float4 ar = *(const float4*)&sAre[kk][c4];
            float4 ai = *(const float4*)&sAim[kk][c4];
#pragma unroll
            for (int i = 0; i < 4; i++) {
                float gx = sGX[r4 + i][kk];
                float gy = sGY[r4 + i][kk];
                accRe[i].x += gx * ar.x - gy * ai.x;
                accRe[i].y += gx * ar.y - gy * ai.y;
                accRe[i].z += gx * ar.z - gy * ai.z;
                accRe[i].w += gx * ar.w - gy * ai.w;
                accIm[i].x += gy * ar.x + gx * ai.x;
                accIm[i].y += gy * ar.y + gx * ai.y;
                accIm[i].z += gy * ar.z + gx * ai.z;
                accIm[i].w += gy * ar.w + gx * ai.w;
            }
        }
        __syncthreads();
    }
#pragma unroll
    for (int i = 0; i < 4; i++) {
        size_t o = (size_t)(m0 + r4 + i) * 128 + c4;
        float4 gx = *(const float4*)(gXf + o);
        float4 gy = *(const float4*)(gYf + o);
        ushort4 sv;
        sv.x = f2b(tanhf(gx.x * accRe[i].x + gy.x * accIm[i].x));
        sv.y = f2b(tanhf(gx.y * accRe[i].y + gy.y * accIm[i].y));
        sv.z = f2b(tanhf(gx.z * accRe[i].z + gy.z * accIm[i].z));
        sv.w = f2b(tanhf(gx.w * accRe[i].w + gy.w * accIm[i].w));
        *(ushort4*)(gf_b + o) = sv;
    }
}

// ------------- last linear: out[m,0:3] = x[m,:] @ w_last + b_last -------------
__global__ __launch_bounds__(256) void last_linear_kern(
    const u16* __restrict__ x, const float* __restrict__ w,
    const float* __restrict__ bias, float* __restrict__ outp, int M)
{
    __shared__ float sw[128 * 3];
    int t = threadIdx.x;
    for (int i = t; i < 384; i += 256) sw[i] = w[i];
    __syncthreads();
    int wave = t >> 6;
    int lane = t & 63;
    int row = blockIdx.x * 4 + wave;
    if (row >= M) return;
    const u16* xr = x + (size_t)row * 128;
    float p0 = 0.f, p1 = 0.f, p2 = 0.f;
#pragma unroll
    for (int h = 0; h < 2; h++) {
        int c = lane + h * 64;
        float xv = b2f(xr[c]);
        p0 += xv * sw[c * 3 + 0];
        p1 += xv * sw[c * 3 + 1];
        p2 += xv * sw[c * 3 + 2];
    }
#pragma unroll
    for (int off = 32; off > 0; off >>= 1) {
        p0 += __shfl_xor(p0, off);
        p1 += __shfl_xor(p1, off);
        p2 += __shfl_xor(p2, off);
    }
    if (lane == 0) {
        float* o = outp + (size_t)row * 3;
        o[0] = p0 + bias[0];
        o[1] = p1 + bias[1];
        o[2] = p2 + bias[2];
    }
}

extern "C" void kernel_launch(void* const* d_in, const int* in_sizes, int n_in,
                              void* d_out, int out_size, void* d_ws, size_t ws_size,
                              hipStream_t stream)
{
    const float* x_in    = (const float*)d_in[0];
    const float* mass    = (const float*)d_in[1];
    const float* evals   = (const float*)d_in[2];
    const float* evecs   = (const float*)d_in[3];
    const int*   rows    = (const int*)  d_in[4];
    const int*   cols    = (const int*)  d_in[5];
    const float* gvx     = (const float*)d_in[6];
    const float* gvy     = (const float*)d_in[7];
    const float* w_first = (const float*)d_in[8];
    const float* b_first = (const float*)d_in[9];
    const float* dtimes  = (const float*)d_in[10];
    const float* A_re    = (const float*)d_in[11];
    const float* A_im    = (const float*)d_in[12];
    const float* w0      = (const float*)d_in[13];
    const float* b0      = (const float*)d_in[14];
    const float* w1      = (const float*)d_in[15];
    const float* b1      = (const float*)d_in[16];
    const float* w2      = (const float*)d_in[17];
    const float* b2      = (const float*)d_in[18];
    const float* w_last  = (const float*)d_in[19];
    const float* b_last  = (const float*)d_in[20];
    float* outp = (float*)d_out;

    const size_t SZ = (size_t)B_ * N_ * 128;   // 20,480,000 elements
    const size_t NZ = (size_t)N_ * 128;        //  5,120,000 elements

    // workspace layout (bf16 activations; ~164 MB total)
    u16* P0 = (u16*)d_ws;                      // 41 MB  (x / xNew ping-pong)
    u16* P1 = P0 + SZ;                         // 41 MB  (xd / xNew ping-pong)
    u16* GF = P1 + SZ;                         // 41 MB  (grad_feat, then h2)
    float* SC = (float*)(GF + SZ);             // 41 MB  f32 scratch: spec partials / per-batch gX,gY / h1(bf16)
    float* ys = SC + 2 * NZ;                   // 0.26 MB f32 coef-applied spectrum

    u16* x  = P0;
    u16* xd = P1;
    const int M = B_ * N_;                     // 160000

    first_linear_kern<<<dim3(M * 128 / 256), 256, 0, stream>>>(x_in, w_first, b_first, x, M);

    for (int i = 0; i < 4; i++) {
        // --- spectral diffusion (deterministic two-stage) ---
        spec_stage1_kern<<<dim3(128, B_), 256, 0, stream>>>(x, mass, evecs, SC);
        spec_stage2_coef_kern<<<dim3(B_ * 128), 128, 0, stream>>>(SC, evals, dtimes + (size_t)i * 128, ys);
        gemm128_kern<128, false, false, false, false, false, true>
            <<<dim3(N_ / 64, 1, B_), 256, 0, stream>>>(
            evecs, nullptr, nullptr, ys, nullptr, nullptr, xd,
            NZ, (size_t)128 * 128, NZ);
        // --- sparse gradients + rotation, one batch at a time (f32 scratch pair) ---
        for (int b = 0; b < B_; b++) {
            hipMemsetAsync(SC, 0, 2 * NZ * sizeof(float), stream);
            spmm_dual_b_kern<<<dim3(E_ * 128 / 256), 256, 0, stream>>>(
                rows, cols, gvx + (size_t)b * E_, gvy + (size_t)b * E_,
                xd + (size_t)b * NZ, SC, SC + NZ);
            rotate_b_kern<<<dim3(N_ / 32), 256, 0, stream>>>(
                SC, SC + NZ, A_re + (size_t)i * 16384, A_im + (size_t)i * 16384,
                GF + (size_t)b * NZ);
        }
        // --- MiniMLP + residual (h1 -> SC as bf16, h2 -> GF, xNew -> xd; swap) ---
        u16* h1 = (u16*)SC;
        gemm128_kern<384, true, true, false, true, true, true>
            <<<dim3(M / 64), 256, 0, stream>>>(
            x, xd, GF, w0 + (size_t)i * 384 * 128, b0 + (size_t)i * 128, nullptr, h1, 0, 0, 0);
        gemm128_kern<128, false, true, false, true, true, true>
            <<<dim3(M / 64), 256, 0, stream>>>(
            h1, nullptr, nullptr, w1 + (size_t)i * 16384, b1 + (size_t)i * 128, nullptr, GF, 0, 0, 0);
        gemm128_kern<128, false, false, true, true, true, true>
            <<<dim3(M / 64), 256, 0, stream>>>(
            GF, nullptr, nullptr, w2 + (size_t)i * 16384, b2 + (size_t)i * 128, x, xd, 0, 0, 0);
        u16* tmp = x; x = xd; xd = tmp;
    }

    last_linear_kern<<<dim3(M / 4), 256, 0, stream>>>(x, w_last, b_last, outp, M);
}

// Round 3
// 6295.246 us; speedup vs baseline: 1.3734x; 1.3734x over previous
//
#include <hip/hip_runtime.h>

#define B_ 4
#define N_ 40000
#define E_ 240000

typedef unsigned short u16;
typedef unsigned int u32;
typedef __attribute__((ext_vector_type(8))) short bf16x8;
typedef __attribute__((ext_vector_type(4))) float f32x4;

__device__ __forceinline__ float b2f(u16 h) {
    u32 u = ((u32)h) << 16;
    return __uint_as_float(u);
}
__device__ __forceinline__ u16 f2b(float f) {
    u32 u = __float_as_uint(f);
    u32 r = (u + 0x7fffu + ((u >> 16) & 1u)) >> 16;
    return (u16)r;
}
__device__ __forceinline__ float4 f4_zero() { return make_float4(0.f, 0.f, 0.f, 0.f); }

// ---------------- first linear: x = x_in @ w_first + b_first (bf16 out) ----------------
__global__ __launch_bounds__(256) void first_linear_kern(
    const float* __restrict__ x_in, const float* __restrict__ w,
    const float* __restrict__ bias, u16* __restrict__ xout, int M)
{
    __shared__ float sw[6 * 128];
    __shared__ float sb[128];
    int t = threadIdx.x;
    for (int i = t; i < 768; i += 256) sw[i] = w[i];
    if (t < 128) sb[t] = bias[t];
    __syncthreads();
    int idx = blockIdx.x * 256 + t;
    int row = idx >> 7;
    int c = idx & 127;
    if (row >= M) return;
    const float* xr = x_in + (size_t)row * 6;
    float acc = sb[c];
#pragma unroll
    for (int j = 0; j < 6; j++) acc += xr[j] * sw[j * 128 + c];
    xout[(size_t)row * 128 + c] = f2b(acc);
}

// ------------- weight pack: dst[n][k] = bf16(src[k][n]), per block i = blockIdx.z -------------
__global__ __launch_bounds__(256) void pack_w_kern(
    const float* __restrict__ src, u16* __restrict__ dst, int K)
{
    int i = blockIdx.z;
    src += (size_t)i * K * 128;
    dst += (size_t)i * K * 128;
    int idx = blockIdx.x * 256 + threadIdx.x;  // = n*K + k
    int n = idx / K;
    int k = idx % K;
    dst[idx] = f2b(src[(size_t)k * 128 + n]);
}

// ------------- spectral projection stage 1 (deterministic partials) -------------
__global__ __launch_bounds__(256) void spec_stage1_kern(
    const u16* __restrict__ x, const float* __restrict__ mass,
    const float* __restrict__ evecs, float* __restrict__ partials)
{
    __shared__ float sEV[32][128];
    __shared__ float sXM[32][128];
    int b = blockIdx.y;
    int pb = blockIdx.x;
    const u16* xb = x + (size_t)b * N_ * 128;
    const float* mb = mass + (size_t)b * N_;
    const float* eb = evecs + (size_t)b * N_ * 128;
    float* dstSlab = partials + ((size_t)b * 128 + pb) * 16384;

    int t = threadIdx.x;
    int c4 = (t & 31) * 4;
    int k0 = (t >> 5) * 16;
    float4 acc[16];
#pragma unroll
    for (int i = 0; i < 16; i++) acc[i] = f4_zero();

    for (int ch = pb; ch < N_ / 32; ch += 128) {
        int n0 = ch * 32;
#pragma unroll
        for (int p = 0; p < 4; p++) {
            int elem = (p * 256 + t) * 4;
            int nn = elem >> 7;
            int kk = elem & 127;
            *(float4*)&sEV[nn][kk] = *(const float4*)(eb + (size_t)(n0 + nn) * 128 + kk);
            float mm = mb[n0 + nn];
            ushort4 xh = *(const ushort4*)(xb + (size_t)(n0 + nn) * 128 + kk);
            float4 xv;
            xv.x = b2f(xh.x) * mm; xv.y = b2f(xh.y) * mm;
            xv.z = b2f(xh.z) * mm; xv.w = b2f(xh.w) * mm;
            *(float4*)&sXM[nn][kk] = xv;
        }
        __syncthreads();
#pragma unroll 2
        for (int nn = 0; nn < 32; nn++) {
            float4 xv = *(const float4*)&sXM[nn][c4];
#pragma unroll
            for (int i = 0; i < 16; i++) {
                float ev = sEV[nn][k0 + i];
                acc[i].x += ev * xv.x;
                acc[i].y += ev * xv.y;
                acc[i].z += ev * xv.z;
                acc[i].w += ev * xv.w;
            }
        }
        __syncthreads();
    }
#pragma unroll
    for (int i = 0; i < 16; i++)
        *(float4*)(dstSlab + (size_t)(k0 + i) * 128 + c4) = acc[i];
}

// ------------- stage 2 + coefficients, TRANSPOSED bf16 out: ys_t[b][c][k] -------------
__global__ __launch_bounds__(128) void spec_stage2_coef_kern(
    const float* __restrict__ partials, const float* __restrict__ evals,
    const float* __restrict__ dt, u16* __restrict__ ys_t)
{
    int b = blockIdx.x >> 7;
    int k = blockIdx.x & 127;
    int c = threadIdx.x;
    const float* p = partials + (size_t)b * 128 * 16384 + (size_t)k * 128 + c;
    float s = 0.f;
#pragma unroll 8
    for (int pb = 0; pb < 128; pb++) s += p[(size_t)pb * 16384];
    float co = expf(-evals[b * 128 + k] * dt[c]);
    ys_t[((size_t)b * 128 + c) * 128 + k] = f2b(s * co);
}

// ------------- MFMA GEMM: out[m,0:128] = act(A[m,:KK] @ W + bias + resid), bf16 out -------------
// A row stride 128 elements (concat parts each 128). Wp is packed transposed bf16 [n][KK].
// grid (M/64, 1, Z); block 256 (4 waves); wave tile 32m x 64n.
template <int KK, bool CONCAT3, bool RELU, bool RESID, bool HASBIAS, bool AF32>
__global__ __launch_bounds__(256) void mgemm_kern(
    const void* __restrict__ A0v, const void* __restrict__ A1v, const void* __restrict__ A2v,
    const u16* __restrict__ Wp, const float* __restrict__ bias,
    const u16* __restrict__ resid, u16* __restrict__ outp,
    size_t aBatch, size_t wBatch, size_t oBatch)
{
    __shared__ u16 sA[64][72];    // padded: 144B row stride
    __shared__ u16 sB[128][72];
    int z = blockIdx.z;
    const u16* Wb = Wp + wBatch * (size_t)z;
    size_t aOff = aBatch * (size_t)z;
    size_t oOff = oBatch * (size_t)z;

    int t = threadIdx.x;
    int m0 = blockIdx.x * 64;
    int wv = t >> 6;
    int lane = t & 63;
    int quad = lane >> 4;
    int r16 = lane & 15;
    int mw = (wv & 1) * 32;
    int nw = (wv >> 1) * 64;

    f32x4 acc[2][4];
#pragma unroll
    for (int i = 0; i < 2; i++)
#pragma unroll
        for (int j = 0; j < 4; j++) acc[i][j] = (f32x4){0.f, 0.f, 0.f, 0.f};

#pragma unroll 1
    for (int kt = 0; kt < KK / 64; kt++) {
        int kbase = kt * 64;
        const void* Ap;
        if (CONCAT3) Ap = (kbase < 128) ? A0v : (kbase < 256) ? A1v : A2v;
        else Ap = A0v;
        int kloc = CONCAT3 ? (kbase & 127) : kbase;

        __syncthreads();
        if (AF32) {
            const float* Af = (const float*)Ap + aOff;
#pragma unroll
            for (int p = 0; p < 4; p++) {
                int idx = p * 256 + t;       // 0..1023
                int row = idx >> 4;          // 64 rows
                int seg = idx & 15;          // 16 segs of 4 floats
                float4 v = *(const float4*)(Af + (size_t)(m0 + row) * 128 + kloc + seg * 4);
                ushort4 h;
                h.x = f2b(v.x); h.y = f2b(v.y); h.z = f2b(v.z); h.w = f2b(v.w);
                *(ushort4*)&sA[row][seg * 4] = h;
            }
        } else {
            const u16* Ah = (const u16*)Ap + aOff;
#pragma unroll
            for (int p = 0; p < 2; p++) {
                int idx = p * 256 + t;       // 0..511
                int row = idx >> 3;          // 64 rows
                int seg = idx & 7;           // 8 segs of 8 u16
                *(uint4*)&sA[row][seg * 8] =
                    *(const uint4*)(Ah + (size_t)(m0 + row) * 128 + kloc + seg * 8);
            }
        }
        {
#pragma unroll
            for (int p = 0; p < 4; p++) {
                int idx = p * 256 + t;       // 0..1023
                int n = idx >> 3;            // 128 n
                int seg = idx & 7;           // 8 segs of 8 u16
                *(uint4*)&sB[n][seg * 8] =
                    *(const uint4*)(Wb + (size_t)n * KK + kbase + seg * 8);
            }
        }
        __syncthreads();

#pragma unroll
        for (int ks = 0; ks < 2; ks++) {
            int ko = ks * 32 + quad * 8;
            bf16x8 a0 = *(const bf16x8*)&sA[mw + r16][ko];
            bf16x8 a1 = *(const bf16x8*)&sA[mw + 16 + r16][ko];
            bf16x8 b0 = *(const bf16x8*)&sB[nw + r16][ko];
            bf16x8 b1 = *(const bf16x8*)&sB[nw + 16 + r16][ko];
            bf16x8 b2 = *(const bf16x8*)&sB[nw + 32 + r16][ko];
            bf16x8 b3 = *(const bf16x8*)&sB[nw + 48 + r16][ko];
            acc[0][0] = __builtin_amdgcn_mfma_f32_16x16x32_bf16(a0, b0, acc[0][0], 0, 0, 0);
            acc[0][1] = __builtin_amdgcn_mfma_f32_16x16x32_bf16(a0, b1, acc[0][1], 0, 0, 0);
            acc[0][2] = __builtin_amdgcn_mfma_f32_16x16x32_bf16(a0, b2, acc[0][2], 0, 0, 0);
            acc[0][3] = __builtin_amdgcn_mfma_f32_16x16x32_bf16(a0, b3, acc[0][3], 0, 0, 0);
            acc[1][0] = __builtin_amdgcn_mfma_f32_16x16x32_bf16(a1, b0, acc[1][0], 0, 0, 0);
            acc[1][1] = __builtin_amdgcn_mfma_f32_16x16x32_bf16(a1, b1, acc[1][1], 0, 0, 0);
            acc[1][2] = __builtin_amdgcn_mfma_f32_16x16x32_bf16(a1, b2, acc[1][2], 0, 0, 0);
            acc[1][3] = __builtin_amdgcn_mfma_f32_16x16x32_bf16(a1, b3, acc[1][3], 0, 0, 0);
        }
    }

    // epilogue: D[row=quad*4+reg][col=r16] per 16x16 tile
#pragma unroll
    for (int nt = 0; nt < 4; nt++) {
        int col = nw + nt * 16 + r16;
        float bv = HASBIAS ? bias[col] : 0.f;
#pragma unroll
        for (int mt = 0; mt < 2; mt++) {
#pragma unroll
            for (int reg = 0; reg < 4; reg++) {
                int row = m0 + mw + mt * 16 + quad * 4 + reg;
                float v = acc[mt][nt][reg] + bv;
                if (RESID) v += b2f(resid[(size_t)row * 128 + col]);
                if (RELU) v = fmaxf(v, 0.f);
                outp[oOff + (size_t)row * 128 + col] = f2b(v);
            }
        }
    }
}

// ------------- single-batch dual COO spMM: gX/gY[row,:] += valX/valY[e] * xd[col,:] -------------
__global__ __launch_bounds__(256) void spmm_dual_b_kern(
    const int* __restrict__ rows, const int* __restrict__ cols,
    const float* __restrict__ vx, const float* __restrict__ vy,
    const u16* __restrict__ xd_b, float* gXf, float* gYf)
{
    int idx = blockIdx.x * 256 + threadIdx.x;
    int e = idx >> 7;
    if (e >= E_) return;
    int c = idx & 127;
    int r = rows[e];
    int col = cols[e];
    float xv = b2f(xd_b[(size_t)col * 128 + c]);
    atomicAdd(gXf + (size_t)r * 128 + c, vx[e] * xv);
    atomicAdd(gYf + (size_t)r * 128 + c, vy[e] * xv);
}

// ------------- rotation + tanh (single batch): gf = tanh(gX*Breal + gY*Bimag) -------------
__global__ __launch_bounds__(256) void rotate_b_kern(
    const float* __restrict__ gXf, const float* __restrict__ gYf,
    const float* __restrict__ Are, const float* __restrict__ Aim,
    u16* __restrict__ gf_b)
{
    __shared__ float sGX[32][32];
    __shared__ float sGY[32][32];
    __shared__ float sAre[32][128];
    __shared__ float sAim[32][128];
    int t = threadIdx.x;
    int m0 = blockIdx.x * 32;
    int c4 = (t & 31) * 4;
    int r4 = (t >> 5) * 4;
    float4 accRe[4], accIm[4];
#pragma unroll
    for (int i = 0; i < 4; i++) { accRe[i] = f4_zero(); accIm[i] = f4_zero(); }

    for (int kt = 0; kt < 4; kt++) {
        int kb = kt * 32;
        {
            int nn = t >> 3;
            int kk = (t & 7) * 4;
            *(float4*)&sGX[nn][kk] = *(const float4*)(gXf + (size_t)(m0 + nn) * 128 + kb + kk);
            *(float4*)&sGY[nn][kk] = *(const float4*)(gYf + (size_t)(m0 + nn) * 128 + kb + kk);
        }
#pragma unroll
        for (int p = 0; p < 4; p++) {
            int elem = (p * 256 + t) * 4;
            int kr = elem >> 7;
            int cc = elem & 127;
            *(float4*)&sAre[kr][cc] = *(const float4*)(Are + (size_t)(kb + kr) * 128 + cc);
            *(float4*)&sAim[kr][cc] = *(const float4*)(Aim + (size_t)(kb + kr) * 128 + cc);
        }
        __syncthreads();
#pragma unroll 4
        for (int kk = 0; kk < 32; kk++) {
            float4 ar = *(const float4*)&sAre[kk][c4];
            float4 ai = *(const float4*)&sAim[kk][c4];
#pragma unroll
            for (int i = 0; i < 4; i++) {
                float gx = sGX[r4 + i][kk];
                float gy = sGY[r4 + i][kk];
                accRe[i].x += gx * ar.x - gy * ai.x;
                accRe[i].y += gx * ar.y - gy * ai.y;
                accRe[i].z += gx * ar.z - gy * ai.z;
                accRe[i].w += gx * ar.w - gy * ai.w;
                accIm[i].x += gy * ar.x + gx * ai.x;
                accIm[i].y += gy * ar.y + gx * ai.y;
                accIm[i].z += gy * ar.z + gx * ai.z;
                accIm[i].w += gy * ar.w + gx * ai.w;
            }
        }
        __syncthreads();
    }
#pragma unroll
    for (int i = 0; i < 4; i++) {
        size_t o = (size_t)(m0 + r4 + i) * 128 + c4;
        float4 gx = *(const float4*)(gXf + o);
        float4 gy = *(const float4*)(gYf + o);
        ushort4 sv;
        sv.x = f2b(tanhf(gx.x * accRe[i].x + gy.x * accIm[i].x));
        sv.y = f2b(tanhf(gx.y * accRe[i].y + gy.y * accIm[i].y));
        sv.z = f2b(tanhf(gx.z * accRe[i].z + gy.z * accIm[i].z));
        sv.w = f2b(tanhf(gx.w * accRe[i].w + gy.w * accIm[i].w));
        *(ushort4*)(gf_b + o) = sv;
    }
}

// ------------- last linear: out[m,0:3] = x[m,:] @ w_last + b_last -------------
__global__ __launch_bounds__(256) void last_linear_kern(
    const u16* __restrict__ x, const float* __restrict__ w,
    const float* __restrict__ bias, float* __restrict__ outp, int M)
{
    __shared__ float sw[128 * 3];
    int t = threadIdx.x;
    for (int i = t; i < 384; i += 256) sw[i] = w[i];
    __syncthreads();
    int wave = t >> 6;
    int lane = t & 63;
    int row = blockIdx.x * 4 + wave;
    if (row >= M) return;
    const u16* xr = x + (size_t)row * 128;
    float p0 = 0.f, p1 = 0.f, p2 = 0.f;
#pragma unroll
    for (int h = 0; h < 2; h++) {
        int c = lane + h * 64;
        float xv = b2f(xr[c]);
        p0 += xv * sw[c * 3 + 0];
        p1 += xv * sw[c * 3 + 1];
        p2 += xv * sw[c * 3 + 2];
    }
#pragma unroll
    for (int off = 32; off > 0; off >>= 1) {
        p0 += __shfl_xor(p0, off);
        p1 += __shfl_xor(p1, off);
        p2 += __shfl_xor(p2, off);
    }
    if (lane == 0) {
        float* o = outp + (size_t)row * 3;
        o[0] = p0 + bias[0];
        o[1] = p1 + bias[1];
        o[2] = p2 + bias[2];
    }
}

extern "C" void kernel_launch(void* const* d_in, const int* in_sizes, int n_in,
                              void* d_out, int out_size, void* d_ws, size_t ws_size,
                              hipStream_t stream)
{
    const float* x_in    = (const float*)d_in[0];
    const float* mass    = (const float*)d_in[1];
    const float* evals   = (const float*)d_in[2];
    const float* evecs   = (const float*)d_in[3];
    const int*   rows    = (const int*)  d_in[4];
    const int*   cols    = (const int*)  d_in[5];
    const float* gvx     = (const float*)d_in[6];
    const float* gvy     = (const float*)d_in[7];
    const float* w_first = (const float*)d_in[8];
    const float* b_first = (const float*)d_in[9];
    const float* dtimes  = (const float*)d_in[10];
    const float* A_re    = (const float*)d_in[11];
    const float* A_im    = (const float*)d_in[12];
    const float* w0      = (const float*)d_in[13];
    const float* b0      = (const float*)d_in[14];
    const float* w1      = (const float*)d_in[15];
    const float* b1      = (const float*)d_in[16];
    const float* w2      = (const float*)d_in[17];
    const float* b2      = (const float*)d_in[18];
    const float* w_last  = (const float*)d_in[19];
    const float* b_last  = (const float*)d_in[20];
    float* outp = (float*)d_out;

    const size_t SZ = (size_t)B_ * N_ * 128;   // 20,480,000 elements
    const size_t NZ = (size_t)N_ * 128;        //  5,120,000 elements

    // workspace layout (~165 MB total, matching the proven round-2 footprint)
    u16* P0 = (u16*)d_ws;                      // 41 MB  (x ping-pong)
    u16* P1 = P0 + SZ;                         // 41 MB  (xd ping-pong)
    u16* GF = P1 + SZ;                         // 41 MB  (grad_feat, then h2)
    float* SC = (float*)(GF + SZ);             // 41 MB  f32: spec partials / per-batch gX,gY / h1
    u16* ys_t = (u16*)(SC + 8388608);          // 128 KB inside SC tail (after partials, before gXgY use)
    u16* WP = (u16*)(SC + 2 * NZ);             // 656 KB packed transposed bf16 weights
    u16* WP0 = WP;                             // 4 x [128][384]
    u16* WP1 = WP0 + 4 * 49152;                // 4 x [128][128]
    u16* WP2 = WP1 + 4 * 16384;                // 4 x [128][128]

    u16* x  = P0;
    u16* xd = P1;
    const int M = B_ * N_;                     // 160000

    // pack weights (once per launch)
    pack_w_kern<<<dim3(192, 1, 4), 256, 0, stream>>>(w0, WP0, 384);
    pack_w_kern<<<dim3(64, 1, 4), 256, 0, stream>>>(w1, WP1, 128);
    pack_w_kern<<<dim3(64, 1, 4), 256, 0, stream>>>(w2, WP2, 128);

    first_linear_kern<<<dim3(M * 128 / 256), 256, 0, stream>>>(x_in, w_first, b_first, x, M);

    for (int i = 0; i < 4; i++) {
        // --- spectral diffusion ---
        spec_stage1_kern<<<dim3(128, B_), 256, 0, stream>>>(x, mass, evecs, SC);
        spec_stage2_coef_kern<<<dim3(B_ * 128), 128, 0, stream>>>(
            SC, evals, dtimes + (size_t)i * 128, ys_t);
        mgemm_kern<128, false, false, false, false, true>
            <<<dim3(N_ / 64, 1, B_), 256, 0, stream>>>(
            evecs, nullptr, nullptr, ys_t, nullptr, nullptr, xd,
            NZ, (size_t)128 * 128, NZ);
        // --- sparse gradients + rotation, per batch ---
        for (int b = 0; b < B_; b++) {
            hipMemsetAsync(SC, 0, 2 * NZ * sizeof(float), stream);
            spmm_dual_b_kern<<<dim3(E_ * 128 / 256), 256, 0, stream>>>(
                rows, cols, gvx + (size_t)b * E_, gvy + (size_t)b * E_,
                xd + (size_t)b * NZ, SC, SC + NZ);
            rotate_b_kern<<<dim3(N_ / 32), 256, 0, stream>>>(
                SC, SC + NZ, A_re + (size_t)i * 16384, A_im + (size_t)i * 16384,
                GF + (size_t)b * NZ);
        }
        // --- MiniMLP + residual ---
        u16* h1 = (u16*)SC;
        mgemm_kern<384, true, true, false, true, false>
            <<<dim3(M / 64), 256, 0, stream>>>(
            x, xd, GF, WP0 + (size_t)i * 49152, b0 + (size_t)i * 128, nullptr, h1, 0, 0, 0);
        mgemm_kern<128, false, true, false, true, false>
            <<<dim3(M / 64), 256, 0, stream>>>(
            h1, nullptr, nullptr, WP1 + (size_t)i * 16384, b1 + (size_t)i * 128, nullptr, GF, 0, 0, 0);
        mgemm_kern<128, false, false, true, true, false>
            <<<dim3(M / 64), 256, 0, stream>>>(
            GF, nullptr, nullptr, WP2 + (size_t)i * 16384, b2 + (size_t)i * 128, x, xd, 0, 0, 0);
        u16* tmp = x; x = xd; xd = tmp;
    }

    last_linear_kern<<<dim3(M / 4), 256, 0, stream>>>(x, w_last, b_last, outp, M);
}

// Round 4
// 2554.842 us; speedup vs baseline: 3.3841x; 2.4640x over previous
//
#include <hip/hip_runtime.h>

#define B_ 4
#define N_ 40000
#define E_ 240000

typedef unsigned short u16;
typedef unsigned int u32;
typedef __attribute__((ext_vector_type(8))) short bf16x8;
typedef __attribute__((ext_vector_type(4))) float f32x4;

__device__ __forceinline__ float b2f(u16 h) {
    u32 u = ((u32)h) << 16;
    return __uint_as_float(u);
}
__device__ __forceinline__ u16 f2b(float f) {
    u32 u = __float_as_uint(f);
    u32 r = (u + 0x7fffu + ((u >> 16) & 1u)) >> 16;
    return (u16)r;
}
__device__ __forceinline__ float4 f4_zero() { return make_float4(0.f, 0.f, 0.f, 0.f); }

// ---------------- first linear: x = x_in @ w_first + b_first (bf16 out) ----------------
__global__ __launch_bounds__(256) void first_linear_kern(
    const float* __restrict__ x_in, const float* __restrict__ w,
    const float* __restrict__ bias, u16* __restrict__ xout, int M)
{
    __shared__ float sw[6 * 128];
    __shared__ float sb[128];
    int t = threadIdx.x;
    for (int i = t; i < 768; i += 256) sw[i] = w[i];
    if (t < 128) sb[t] = bias[t];
    __syncthreads();
    int idx = blockIdx.x * 256 + t;
    int row = idx >> 7;
    int c = idx & 127;
    if (row >= M) return;
    const float* xr = x_in + (size_t)row * 6;
    float acc = sb[c];
#pragma unroll
    for (int j = 0; j < 6; j++) acc += xr[j] * sw[j * 128 + c];
    xout[(size_t)row * 128 + c] = f2b(acc);
}

// ------------- weight pack: dst[n][k] = bf16(src[k][n]), per block i = blockIdx.z -------------
__global__ __launch_bounds__(256) void pack_w_kern(
    const float* __restrict__ src, u16* __restrict__ dst, int K)
{
    int i = blockIdx.z;
    src += (size_t)i * K * 128;
    dst += (size_t)i * K * 128;
    int idx = blockIdx.x * 256 + threadIdx.x;  // = n*K + k
    int n = idx / K;
    int k = idx % K;
    dst[idx] = f2b(src[(size_t)k * 128 + n]);
}

// ------------- rotation weight pack: WR1[n][k256] = [Are; -Aim]^T, WR2 = [Are; Aim]^T -------------
__global__ __launch_bounds__(256) void pack_rot_kern(
    const float* __restrict__ Are, const float* __restrict__ Aim,
    u16* __restrict__ WR1, u16* __restrict__ WR2)
{
    int i = blockIdx.z;
    const float* are = Are + (size_t)i * 16384;
    const float* aim = Aim + (size_t)i * 16384;
    int idx = blockIdx.x * 256 + threadIdx.x;  // 0..32767 = n*256 + k
    int n = idx >> 8;
    int k = idx & 255;
    float v1, v2;
    if (k < 128) { float a = are[(size_t)k * 128 + n]; v1 = a; v2 = a; }
    else         { float a = aim[(size_t)(k - 128) * 128 + n]; v1 = -a; v2 = a; }
    WR1[(size_t)i * 32768 + idx] = f2b(v1);
    WR2[(size_t)i * 32768 + idx] = f2b(v2);
}

// ------------- CSR build: histogram -> scan -> scatter (shared pattern, all batches) -------------
__global__ __launch_bounds__(256) void hist_kern(const int* __restrict__ rows, int* count)
{
    int e = blockIdx.x * 256 + threadIdx.x;
    if (e < E_) atomicAdd(&count[rows[e]], 1);
}

__global__ __launch_bounds__(256) void scan_kern(
    const int* __restrict__ count, int* __restrict__ rowptr, int* __restrict__ nextp)
{
    __shared__ int buf[256];
    __shared__ int carry_s;
    int t = threadIdx.x;
    if (t == 0) carry_s = 0;
    __syncthreads();
    for (int base = 0; base < N_; base += 256) {
        int v = (base + t < N_) ? count[base + t] : 0;
        buf[t] = v;
        __syncthreads();
#pragma unroll
        for (int off = 1; off < 256; off <<= 1) {
            int add = (t >= off) ? buf[t - off] : 0;
            __syncthreads();
            buf[t] += add;
            __syncthreads();
        }
        int incl = buf[t];
        int excl = incl - v;
        int c = carry_s;
        if (base + t < N_) {
            rowptr[base + t] = c + excl;
            nextp[base + t]  = c + excl;
        }
        __syncthreads();
        if (t == 255) carry_s = c + incl;
        __syncthreads();
    }
    if (t == 0) rowptr[N_] = carry_s;
}

__global__ __launch_bounds__(256) void scatter_kern(
    const int* __restrict__ rows, const int* __restrict__ cols,
    const float* __restrict__ gvx, const float* __restrict__ gvy,
    int* nextp, int* __restrict__ scols,
    float* __restrict__ svx, float* __restrict__ svy)
{
    int e = blockIdx.x * 256 + threadIdx.x;
    if (e >= E_) return;
    int r = rows[e];
    int pos = atomicAdd(&nextp[r], 1);
    scols[pos] = cols[e];
#pragma unroll
    for (int b = 0; b < B_; b++) {
        svx[(size_t)b * E_ + pos] = gvx[(size_t)b * E_ + e];
        svy[(size_t)b * E_ + pos] = gvy[(size_t)b * E_ + e];
    }
}

// ------------- CSR dual spMM (single batch): gX/gY[r,:] = sum_j val[j]*xd[scols[j],:] -------------
__global__ __launch_bounds__(256) void spmm_csr_kern(
    const int* __restrict__ rowptr, const int* __restrict__ scols,
    const float* __restrict__ svx, const float* __restrict__ svy,
    const u16* __restrict__ xd_b, float* __restrict__ gXf, float* __restrict__ gYf)
{
    int t = threadIdx.x;
    int r = blockIdx.x * 2 + (t >> 7);
    int c = t & 127;
    int beg = rowptr[r], end = rowptr[r + 1];
    float ax = 0.f, ay = 0.f;
    for (int j = beg; j < end; j++) {
        int col = scols[j];
        float xv = b2f(xd_b[(size_t)col * 128 + c]);
        ax += svx[j] * xv;
        ay += svy[j] * xv;
    }
    gXf[(size_t)r * 128 + c] = ax;
    gYf[(size_t)r * 128 + c] = ay;
}

// ------------- spectral projection stage 1 (deterministic partials) -------------
__global__ __launch_bounds__(256) void spec_stage1_kern(
    const u16* __restrict__ x, const float* __restrict__ mass,
    const float* __restrict__ evecs, float* __restrict__ partials)
{
    __shared__ float sEV[32][128];
    __shared__ float sXM[32][128];
    int b = blockIdx.y;
    int pb = blockIdx.x;
    const u16* xb = x + (size_t)b * N_ * 128;
    const float* mb = mass + (size_t)b * N_;
    const float* eb = evecs + (size_t)b * N_ * 128;
    float* dstSlab = partials + ((size_t)b * 128 + pb) * 16384;

    int t = threadIdx.x;
    int c4 = (t & 31) * 4;
    int k0 = (t >> 5) * 16;
    float4 acc[16];
#pragma unroll
    for (int i = 0; i < 16; i++) acc[i] = f4_zero();

    for (int ch = pb; ch < N_ / 32; ch += 128) {
        int n0 = ch * 32;
#pragma unroll
        for (int p = 0; p < 4; p++) {
            int elem = (p * 256 + t) * 4;
            int nn = elem >> 7;
            int kk = elem & 127;
            *(float4*)&sEV[nn][kk] = *(const float4*)(eb + (size_t)(n0 + nn) * 128 + kk);
            float mm = mb[n0 + nn];
            ushort4 xh = *(const ushort4*)(xb + (size_t)(n0 + nn) * 128 + kk);
            float4 xv;
            xv.x = b2f(xh.x) * mm; xv.y = b2f(xh.y) * mm;
            xv.z = b2f(xh.z) * mm; xv.w = b2f(xh.w) * mm;
            *(float4*)&sXM[nn][kk] = xv;
        }
        __syncthreads();
#pragma unroll 2
        for (int nn = 0; nn < 32; nn++) {
            float4 xv = *(const float4*)&sXM[nn][c4];
#pragma unroll
            for (int i = 0; i < 16; i++) {
                float ev = sEV[nn][k0 + i];
                acc[i].x += ev * xv.x;
                acc[i].y += ev * xv.y;
                acc[i].z += ev * xv.z;
                acc[i].w += ev * xv.w;
            }
        }
        __syncthreads();
    }
#pragma unroll
    for (int i = 0; i < 16; i++)
        *(float4*)(dstSlab + (size_t)(k0 + i) * 128 + c4) = acc[i];
}

// ------------- stage 2 + coefficients, TRANSPOSED bf16 out: ys_t[b][c][k] -------------
__global__ __launch_bounds__(128) void spec_stage2_coef_kern(
    const float* __restrict__ partials, const float* __restrict__ evals,
    const float* __restrict__ dt, u16* __restrict__ ys_t)
{
    int b = blockIdx.x >> 7;
    int k = blockIdx.x & 127;
    int c = threadIdx.x;
    const float* p = partials + (size_t)b * 128 * 16384 + (size_t)k * 128 + c;
    float s = 0.f;
#pragma unroll 8
    for (int pb = 0; pb < 128; pb++) s += p[(size_t)pb * 16384];
    float co = expf(-evals[b * 128 + k] * dt[c]);
    ys_t[((size_t)b * 128 + c) * 128 + k] = f2b(s * co);
}

// ------------- MFMA GEMM: out[m,0:128] = act(A[m,:KK] @ W + bias + resid), bf16 out -------------
template <int KK, bool CONCAT3, bool RELU, bool RESID, bool HASBIAS, bool AF32>
__global__ __launch_bounds__(256) void mgemm_kern(
    const void* __restrict__ A0v, const void* __restrict__ A1v, const void* __restrict__ A2v,
    const u16* __restrict__ Wp, const float* __restrict__ bias,
    const u16* __restrict__ resid, u16* __restrict__ outp,
    size_t aBatch, size_t wBatch, size_t oBatch)
{
    __shared__ u16 sA[64][72];    // padded: 144B row stride
    __shared__ u16 sB[128][72];
    int z = blockIdx.z;
    const u16* Wb = Wp + wBatch * (size_t)z;
    size_t aOff = aBatch * (size_t)z;
    size_t oOff = oBatch * (size_t)z;

    int t = threadIdx.x;
    int m0 = blockIdx.x * 64;
    int wv = t >> 6;
    int lane = t & 63;
    int quad = lane >> 4;
    int r16 = lane & 15;
    int mw = (wv & 1) * 32;
    int nw = (wv >> 1) * 64;

    f32x4 acc[2][4];
#pragma unroll
    for (int i = 0; i < 2; i++)
#pragma unroll
        for (int j = 0; j < 4; j++) acc[i][j] = (f32x4){0.f, 0.f, 0.f, 0.f};

#pragma unroll 1
    for (int kt = 0; kt < KK / 64; kt++) {
        int kbase = kt * 64;
        const void* Ap;
        if (CONCAT3) Ap = (kbase < 128) ? A0v : (kbase < 256) ? A1v : A2v;
        else Ap = A0v;
        int kloc = CONCAT3 ? (kbase & 127) : kbase;

        __syncthreads();
        if (AF32) {
            const float* Af = (const float*)Ap + aOff;
#pragma unroll
            for (int p = 0; p < 4; p++) {
                int idx = p * 256 + t;       // 0..1023
                int row = idx >> 4;          // 64 rows
                int seg = idx & 15;          // 16 segs of 4 floats
                float4 v = *(const float4*)(Af + (size_t)(m0 + row) * 128 + kloc + seg * 4);
                ushort4 h;
                h.x = f2b(v.x); h.y = f2b(v.y); h.z = f2b(v.z); h.w = f2b(v.w);
                *(ushort4*)&sA[row][seg * 4] = h;
            }
        } else {
            const u16* Ah = (const u16*)Ap + aOff;
#pragma unroll
            for (int p = 0; p < 2; p++) {
                int idx = p * 256 + t;       // 0..511
                int row = idx >> 3;          // 64 rows
                int seg = idx & 7;           // 8 segs of 8 u16
                *(uint4*)&sA[row][seg * 8] =
                    *(const uint4*)(Ah + (size_t)(m0 + row) * 128 + kloc + seg * 8);
            }
        }
        {
#pragma unroll
            for (int p = 0; p < 4; p++) {
                int idx = p * 256 + t;       // 0..1023
                int n = idx >> 3;            // 128 n
                int seg = idx & 7;           // 8 segs of 8 u16
                *(uint4*)&sB[n][seg * 8] =
                    *(const uint4*)(Wb + (size_t)n * KK + kbase + seg * 8);
            }
        }
        __syncthreads();

#pragma unroll
        for (int ks = 0; ks < 2; ks++) {
            int ko = ks * 32 + quad * 8;
            bf16x8 a0 = *(const bf16x8*)&sA[mw + r16][ko];
            bf16x8 a1 = *(const bf16x8*)&sA[mw + 16 + r16][ko];
            bf16x8 b0 = *(const bf16x8*)&sB[nw + r16][ko];
            bf16x8 b1 = *(const bf16x8*)&sB[nw + 16 + r16][ko];
            bf16x8 b2 = *(const bf16x8*)&sB[nw + 32 + r16][ko];
            bf16x8 b3 = *(const bf16x8*)&sB[nw + 48 + r16][ko];
            acc[0][0] = __builtin_amdgcn_mfma_f32_16x16x32_bf16(a0, b0, acc[0][0], 0, 0, 0);
            acc[0][1] = __builtin_amdgcn_mfma_f32_16x16x32_bf16(a0, b1, acc[0][1], 0, 0, 0);
            acc[0][2] = __builtin_amdgcn_mfma_f32_16x16x32_bf16(a0, b2, acc[0][2], 0, 0, 0);
            acc[0][3] = __builtin_amdgcn_mfma_f32_16x16x32_bf16(a0, b3, acc[0][3], 0, 0, 0);
            acc[1][0] = __builtin_amdgcn_mfma_f32_16x16x32_bf16(a1, b0, acc[1][0], 0, 0, 0);
            acc[1][1] = __builtin_amdgcn_mfma_f32_16x16x32_bf16(a1, b1, acc[1][1], 0, 0, 0);
            acc[1][2] = __builtin_amdgcn_mfma_f32_16x16x32_bf16(a1, b2, acc[1][2], 0, 0, 0);
            acc[1][3] = __builtin_amdgcn_mfma_f32_16x16x32_bf16(a1, b3, acc[1][3], 0, 0, 0);
        }
    }

    // epilogue: D[row=quad*4+reg][col=r16] per 16x16 tile
#pragma unroll
    for (int nt = 0; nt < 4; nt++) {
        int col = nw + nt * 16 + r16;
        float bv = HASBIAS ? bias[col] : 0.f;
#pragma unroll
        for (int mt = 0; mt < 2; mt++) {
#pragma unroll
            for (int reg = 0; reg < 4; reg++) {
                int row = m0 + mw + mt * 16 + quad * 4 + reg;
                float v = acc[mt][nt][reg] + bv;
                if (RESID) v += b2f(resid[(size_t)row * 128 + col]);
                if (RELU) v = fmaxf(v, 0.f);
                outp[oOff + (size_t)row * 128 + col] = f2b(v);
            }
        }
    }
}

// ------------- MFMA rotation + tanh (single batch) -------------
// Breal = [gX|gY] @ WR1, Bimag = [gY|gX] @ WR2 (K=256), gf = tanh(gX*Breal + gY*Bimag)
__global__ __launch_bounds__(256) void rotate_mfma_kern(
    const float* __restrict__ gXf, const float* __restrict__ gYf,
    const u16* __restrict__ WR1, const u16* __restrict__ WR2,
    u16* __restrict__ gf_b)
{
    __shared__ u16 sGX[64][136];  // 64 rows x K=128 (+8 pad)
    __shared__ u16 sGY[64][136];
    __shared__ u16 sB1[128][72];  // n x 64-k chunk
    __shared__ u16 sB2[128][72];

    int t = threadIdx.x;
    int m0 = blockIdx.x * 64;
    int wv = t >> 6;
    int lane = t & 63;
    int quad = lane >> 4;
    int r16 = lane & 15;
    int mw = (wv & 1) * 32;
    int nw = (wv >> 1) * 64;

    // stage gX, gY (f32 -> bf16), full K
#pragma unroll
    for (int p = 0; p < 8; p++) {
        int idx = p * 256 + t;           // 0..2047
        int row = idx >> 5;              // 64 rows
        int seg = idx & 31;              // 32 segs of 4 floats
        float4 vx = *(const float4*)(gXf + (size_t)(m0 + row) * 128 + seg * 4);
        float4 vy = *(const float4*)(gYf + (size_t)(m0 + row) * 128 + seg * 4);
        ushort4 hx, hy;
        hx.x = f2b(vx.x); hx.y = f2b(vx.y); hx.z = f2b(vx.z); hx.w = f2b(vx.w);
        hy.x = f2b(vy.x); hy.y = f2b(vy.y); hy.z = f2b(vy.z); hy.w = f2b(vy.w);
        *(ushort4*)&sGX[row][seg * 4] = hx;
        *(ushort4*)&sGY[row][seg * 4] = hy;
    }

    f32x4 accRe[2][4], accIm[2][4];
#pragma unroll
    for (int i = 0; i < 2; i++)
#pragma unroll
        for (int j = 0; j < 4; j++) {
            accRe[i][j] = (f32x4){0.f, 0.f, 0.f, 0.f};
            accIm[i][j] = (f32x4){0.f, 0.f, 0.f, 0.f};
        }

#pragma unroll 1
    for (int c = 0; c < 4; c++) {
        __syncthreads();
        // stage WR1/WR2 chunk [128][64]
#pragma unroll
        for (int p = 0; p < 4; p++) {
            int idx = p * 256 + t;       // 0..1023
            int n = idx >> 3;
            int seg = idx & 7;
            *(uint4*)&sB1[n][seg * 8] = *(const uint4*)(WR1 + (size_t)n * 256 + c * 64 + seg * 8);
            *(uint4*)&sB2[n][seg * 8] = *(const uint4*)(WR2 + (size_t)n * 256 + c * 64 + seg * 8);
        }
        __syncthreads();

        const u16 (*sRe)[136] = (c < 2) ? sGX : sGY;
        const u16 (*sIm)[136] = (c < 2) ? sGY : sGX;
        int kob = (c & 1) * 64;
#pragma unroll
        for (int ks = 0; ks < 2; ks++) {
            int ko = kob + ks * 32 + quad * 8;
            int kb = ks * 32 + quad * 8;
            bf16x8 aRe0 = *(const bf16x8*)&sRe[mw + r16][ko];
            bf16x8 aRe1 = *(const bf16x8*)&sRe[mw + 16 + r16][ko];
            bf16x8 aIm0 = *(const bf16x8*)&sIm[mw + r16][ko];
            bf16x8 aIm1 = *(const bf16x8*)&sIm[mw + 16 + r16][ko];
#pragma unroll
            for (int j = 0; j < 4; j++) {
                bf16x8 b1 = *(const bf16x8*)&sB1[nw + 16 * j + r16][kb];
                bf16x8 b2 = *(const bf16x8*)&sB2[nw + 16 * j + r16][kb];
                accRe[0][j] = __builtin_amdgcn_mfma_f32_16x16x32_bf16(aRe0, b1, accRe[0][j], 0, 0, 0);
                accRe[1][j] = __builtin_amdgcn_mfma_f32_16x16x32_bf16(aRe1, b1, accRe[1][j], 0, 0, 0);
                accIm[0][j] = __builtin_amdgcn_mfma_f32_16x16x32_bf16(aIm0, b2, accIm[0][j], 0, 0, 0);
                accIm[1][j] = __builtin_amdgcn_mfma_f32_16x16x32_bf16(aIm1, b2, accIm[1][j], 0, 0, 0);
            }
        }
    }

    // epilogue: gf = tanh(gX*Breal + gY*Bimag)
#pragma unroll
    for (int nt = 0; nt < 4; nt++) {
        int col = nw + nt * 16 + r16;
#pragma unroll
        for (int mt = 0; mt < 2; mt++) {
#pragma unroll
            for (int reg = 0; reg < 4; reg++) {
                int row = m0 + mw + mt * 16 + quad * 4 + reg;
                float gx = gXf[(size_t)row * 128 + col];
                float gy = gYf[(size_t)row * 128 + col];
                float v = tanhf(gx * accRe[mt][nt][reg] + gy * accIm[mt][nt][reg]);
                gf_b[(size_t)row * 128 + col] = f2b(v);
            }
        }
    }
}

// ------------- last linear: out[m,0:3] = x[m,:] @ w_last + b_last -------------
__global__ __launch_bounds__(256) void last_linear_kern(
    const u16* __restrict__ x, const float* __restrict__ w,
    const float* __restrict__ bias, float* __restrict__ outp, int M)
{
    __shared__ float sw[128 * 3];
    int t = threadIdx.x;
    for (int i = t; i < 384; i += 256) sw[i] = w[i];
    __syncthreads();
    int wave = t >> 6;
    int lane = t & 63;
    int row = blockIdx.x * 4 + wave;
    if (row >= M) return;
    const u16* xr = x + (size_t)row * 128;
    float p0 = 0.f, p1 = 0.f, p2 = 0.f;
#pragma unroll
    for (int h = 0; h < 2; h++) {
        int c = lane + h * 64;
        float xv = b2f(xr[c]);
        p0 += xv * sw[c * 3 + 0];
        p1 += xv * sw[c * 3 + 1];
        p2 += xv * sw[c * 3 + 2];
    }
#pragma unroll
    for (int off = 32; off > 0; off >>= 1) {
        p0 += __shfl_xor(p0, off);
        p1 += __shfl_xor(p1, off);
        p2 += __shfl_xor(p2, off);
    }
    if (lane == 0) {
        float* o = outp + (size_t)row * 3;
        o[0] = p0 + bias[0];
        o[1] = p1 + bias[1];
        o[2] = p2 + bias[2];
    }
}

extern "C" void kernel_launch(void* const* d_in, const int* in_sizes, int n_in,
                              void* d_out, int out_size, void* d_ws, size_t ws_size,
                              hipStream_t stream)
{
    const float* x_in    = (const float*)d_in[0];
    const float* mass    = (const float*)d_in[1];
    const float* evals   = (const float*)d_in[2];
    const float* evecs   = (const float*)d_in[3];
    const int*   rows    = (const int*)  d_in[4];
    const int*   cols    = (const int*)  d_in[5];
    const float* gvx     = (const float*)d_in[6];
    const float* gvy     = (const float*)d_in[7];
    const float* w_first = (const float*)d_in[8];
    const float* b_first = (const float*)d_in[9];
    const float* dtimes  = (const float*)d_in[10];
    const float* A_re    = (const float*)d_in[11];
    const float* A_im    = (const float*)d_in[12];
    const float* w0      = (const float*)d_in[13];
    const float* b0      = (const float*)d_in[14];
    const float* w1      = (const float*)d_in[15];
    const float* b1      = (const float*)d_in[16];
    const float* w2      = (const float*)d_in[17];
    const float* b2      = (const float*)d_in[18];
    const float* w_last  = (const float*)d_in[19];
    const float* b_last  = (const float*)d_in[20];
    float* outp = (float*)d_out;

    const size_t SZ = (size_t)B_ * N_ * 128;   // 20,480,000 elements
    const size_t NZ = (size_t)N_ * 128;        //  5,120,000 elements

    // workspace layout (~174 MB)
    u16* P0 = (u16*)d_ws;                      // 41 MB  (x ping-pong)
    u16* P1 = P0 + SZ;                         // 41 MB  (xd ping-pong)
    u16* GF = P1 + SZ;                         // 41 MB  (grad_feat, then h2)
    float* SC = (float*)(GF + SZ);             // 41 MB  f32: spec partials / per-batch gX,gY / h1
    u16* ys_t = (u16*)(SC + 8388608);          // 128 KB inside SC tail
    u16* WP0 = (u16*)(SC + 2 * NZ);            // packed transposed bf16 weights
    u16* WP1 = WP0 + 4 * 49152;
    u16* WP2 = WP1 + 4 * 16384;
    u16* WR1 = WP2 + 4 * 16384;                // 4 x [128][256] rotation packs
    u16* WR2 = WR1 + 4 * 32768;
    int* rowptr = (int*)(WR2 + 4 * 32768);     // N+1 (padded to 40004)
    int* nextp  = rowptr + 40004;              // N (histogram counts, then cursors)
    int* scols  = nextp + N_;                  // E sorted cols
    float* svx  = (float*)(scols + E_);        // [B][E] sorted vals
    float* svy  = svx + (size_t)B_ * E_;

    u16* x  = P0;
    u16* xd = P1;
    const int M = B_ * N_;                     // 160000

    // --- CSR build (pattern shared across blocks & X/Y) ---
    hipMemsetAsync(nextp, 0, N_ * sizeof(int), stream);
    hist_kern<<<dim3((E_ + 255) / 256), 256, 0, stream>>>(rows, nextp);
    scan_kern<<<dim3(1), 256, 0, stream>>>(nextp, rowptr, nextp);
    scatter_kern<<<dim3((E_ + 255) / 256), 256, 0, stream>>>(
        rows, cols, gvx, gvy, nextp, scols, svx, svy);

    // --- weight packing (once per launch) ---
    pack_w_kern<<<dim3(192, 1, 4), 256, 0, stream>>>(w0, WP0, 384);
    pack_w_kern<<<dim3(64, 1, 4), 256, 0, stream>>>(w1, WP1, 128);
    pack_w_kern<<<dim3(64, 1, 4), 256, 0, stream>>>(w2, WP2, 128);
    pack_rot_kern<<<dim3(128, 1, 4), 256, 0, stream>>>(A_re, A_im, WR1, WR2);

    first_linear_kern<<<dim3(M * 128 / 256), 256, 0, stream>>>(x_in, w_first, b_first, x, M);

    for (int i = 0; i < 4; i++) {
        // --- spectral diffusion ---
        spec_stage1_kern<<<dim3(128, B_), 256, 0, stream>>>(x, mass, evecs, SC);
        spec_stage2_coef_kern<<<dim3(B_ * 128), 128, 0, stream>>>(
            SC, evals, dtimes + (size_t)i * 128, ys_t);
        mgemm_kern<128, false, false, false, false, true>
            <<<dim3(N_ / 64, 1, B_), 256, 0, stream>>>(
            evecs, nullptr, nullptr, ys_t, nullptr, nullptr, xd,
            NZ, (size_t)128 * 128, NZ);
        // --- sparse gradients (CSR, no atomics) + MFMA rotation, per batch ---
        for (int b = 0; b < B_; b++) {
            spmm_csr_kern<<<dim3(N_ / 2), 256, 0, stream>>>(
                rowptr, scols, svx + (size_t)b * E_, svy + (size_t)b * E_,
                xd + (size_t)b * NZ, SC, SC + NZ);
            rotate_mfma_kern<<<dim3(N_ / 64), 256, 0, stream>>>(
                SC, SC + NZ, WR1 + (size_t)i * 32768, WR2 + (size_t)i * 32768,
                GF + (size_t)b * NZ);
        }
        // --- MiniMLP + residual ---
        u16* h1 = (u16*)SC;
        mgemm_kern<384, true, true, false, true, false>
            <<<dim3(M / 64), 256, 0, stream>>>(
            x, xd, GF, WP0 + (size_t)i * 49152, b0 + (size_t)i * 128, nullptr, h1, 0, 0, 0);
        mgemm_kern<128, false, true, false, true, false>
            <<<dim3(M / 64), 256, 0, stream>>>(
            h1, nullptr, nullptr, WP1 + (size_t)i * 16384, b1 + (size_t)i * 128, nullptr, GF, 0, 0, 0);
        mgemm_kern<128, false, false, true, true, false>
            <<<dim3(M / 64), 256, 0, stream>>>(
            GF, nullptr, nullptr, WP2 + (size_t)i * 16384, b2 + (size_t)i * 128, x, xd, 0, 0, 0);
        u16* tmp = x; x = xd; xd = tmp;
    }

    last_linear_kern<<<dim3(M / 4), 256, 0, stream>>>(x, w_last, b_last, outp, M);
}